// Round 7
// baseline (2384.739 us; speedup 1.0000x reference)
//
#include <hip/hip_runtime.h>
#include <hip/hip_bf16.h>
#include <math.h>

// ============================================================================
// ResponseFilter — round 9: de-serialized K-loop (1 barrier/K-tile) + T1.
//
// Round-8 post-mortem: 8-phase at K=768 left 1450 cyc/phase of non-MFMA —
// the 2-barriers-per-phase lockstep serialized LDS-pipe time (ds_reads,
// up to 768 cyc at p0) with MFMA-pipe time (620 cyc), 8x per K-tile.
// This round: ONE {vmcnt(0); s_barrier} per K-tile + full-tile prefetch
// (stage kt+1 right after barrier(kt); loads get a whole tile-compute of
// cover so vmcnt(0) is ~free). Waves free-run inside the tile: 24 ds_reads
// + 64 MFMAs per wave, compiler-scheduled lgkmcnt, setprio around MFMAs.
// Race-safe: barrier(kt) orders all reads of buf[nxt] (tile kt-1, program-
// order before the barrier in every wave) before any STG(kt+1) into it.
// Plus T1: bijective XCD-chunked swizzle on linear block id (consecutive
// ids share the B panel -> panel stays L2-resident per XCD; FETCH was
// 2.4x unique bytes).
// LDS layout / staging indices / epilogue identical to round 8 (verified).
// Attention (KV-resident), LN (wave-per-row), everything else unchanged.
// ============================================================================

#define B_  16
#define T_  32
#define L_  64
#define D_  768
#define H_  12
#define F_  2048
#define ZR_ 100
#define ZP_ 128
#define NP_ 512
#define EPS_ 1e-5f

// meta int offsets (d_ws as int*)
#define MI_NTOT  0
#define MI_NRESP 8
#define MI_OFF   32
#define MI_BIDX  64
#define MI_TIDX  576
#define MI_NODE  1088

// ws float offsets
#define WS_BIAS2 2048
#define WS_EMEAN 34816
#define WS_S     428032
#define WS_WST   428544    // bf16 weight stage, 1,769,472 ushorts (3.54 MB)
#define WS_BIG   1313280   // bf16 QKV/hidden region; fp32 Z overlay

// d_out float offsets (flat tuple: oh[512], ext_mask[32768], n_ext_adv[1],
// new_tree_lens[16], new_emb[25165824], new_msk[32768])
#define OUT_OH   0
#define OUT_EXT  512
#define OUT_NEA  33280
#define OUT_NTL  33281
#define OUT_NEMB 33297
#define OUT_NMSK 25199121
#define OUT_XSCR 33300   // bf16 X scratch (16B aligned), 32768*768 ushorts

typedef __attribute__((ext_vector_type(8))) short short8;
typedef __attribute__((ext_vector_type(4))) float f32x4;

__device__ inline float bf2f(unsigned s) {
  return __uint_as_float((s & 0xffffu) << 16);
}
__device__ inline unsigned short f2bf(float x) {
  unsigned u = __float_as_uint(x);
  u += 0x7fffu + ((u >> 16) & 1u);      // round-to-nearest-even
  return (unsigned short)(u >> 16);
}
__device__ inline unsigned pack2(float a, float b) {
  return (unsigned)f2bf(a) | ((unsigned)f2bf(b) << 16);
}

// ---------------------------------------------------------------------------
__global__ void meta_kernel(const int* __restrict__ tl, int* __restrict__ mi) {
  if (threadIdx.x != 0) return;
  int off = 0;
  for (int b = 0; b < B_; b++) {
    int nr = tl[b] - 1;
    mi[MI_NRESP + b] = nr;
    mi[MI_OFF + b] = off;
    off += nr;
  }
  mi[MI_NTOT] = off;
  for (int j = 0; j < NP_; j++) {
    int b = -1, t = 0;
    if (j < off) {
      b = 0;
      while (b + 1 < B_ && j >= mi[MI_OFF + b + 1]) b++;
      t = j - mi[MI_OFF + b] + 1;
    }
    mi[MI_BIDX + j] = b;
    mi[MI_TIDX + j] = t;
  }
}

// ---------------------------------------------------------------------------
// fp32 -> bf16 weight conversion (n multiple of 1024)
__global__ __launch_bounds__(256) void w2bf_kernel(const float* __restrict__ W,
                                                   unsigned short* __restrict__ o) {
  const int i = (blockIdx.x * 256 + threadIdx.x) * 4;
  float4 v = *(const float4*)(W + i);
  uint2 pk; pk.x = pack2(v.x, v.y); pk.y = pack2(v.z, v.w);
  *(uint2*)(o + i) = pk;
}

// ---------------------------------------------------------------------------
// X[j,l,:] bf16 = reply embedding (zero for padded j); bias2 = mask or -1e30
__global__ __launch_bounds__(192) void gather_kernel(
    const float* __restrict__ emb, const float* __restrict__ am,
    const int* __restrict__ mi, unsigned short* __restrict__ X,
    float* __restrict__ bias2) {
  const int blk = blockIdx.x;          // j*64 + l
  const int j = blk >> 6, l = blk & 63;
  const int ntot = mi[MI_NTOT];
  const int t = threadIdx.x;
  float4 v = make_float4(0.f, 0.f, 0.f, 0.f);
  if (j < ntot) {
    const int b = mi[MI_BIDX + j], tt = mi[MI_TIDX + j];
    v = ((const float4*)(emb + (size_t)((b * T_ + tt) * L_ + l) * D_))[t];
    if (t == 0) bias2[blk] = am[(b * T_ + tt) * L_ + l];
  } else {
    if (t == 0) bias2[blk] = -1e30f;
  }
  uint2 pk; pk.x = pack2(v.x, v.y); pk.y = pack2(v.z, v.w);
  *(uint2*)(X + (size_t)blk * D_ + t * 4) = pk;
}

// ---------------------------------------------------------------------------
__global__ __launch_bounds__(256) void emean_kernel(const unsigned short* __restrict__ X,
                                                    float* __restrict__ em) {
  const int j = blockIdx.x;
  int d = threadIdx.x;
  for (int c = 0; c < 3; c++, d += 256) {
    const unsigned short* p = X + (size_t)j * L_ * D_ + d;
    float s = 0.f;
    for (int l = 0; l < L_; l++) s += bf2f(p[l * D_]);
    em[j * D_ + d] = s * (1.f / 64.f);
  }
}

// ---------------------------------------------------------------------------
__device__ inline float blockSum256(float v, float* red) {
  #pragma unroll
  for (int o = 32; o > 0; o >>= 1) v += __shfl_down(v, o);
  const int lane = threadIdx.x & 63, wid = threadIdx.x >> 6;
  __syncthreads();
  if (lane == 0) red[wid] = v;
  __syncthreads();
  return red[0] + red[1] + red[2] + red[3];
}

// in-place LN, wave-per-row (4 rows/block, no barriers); skips padded rows
__global__ __launch_bounds__(256) void ln_kernel(unsigned short* __restrict__ X,
                                                 const float* __restrict__ g,
                                                 const float* __restrict__ bb,
                                                 const int* __restrict__ mi) {
  const int row = blockIdx.x * 4 + (threadIdx.x >> 6);
  if (row >= mi[MI_NTOT] * L_) return;
  const int lane = threadIdx.x & 63;
  unsigned short* p = X + (size_t)row * D_;
  float v[12];
  #pragma unroll
  for (int c = 0; c < 3; c++) {
    uint2 u = *(const uint2*)(p + lane * 4 + c * 256);
    v[c * 4 + 0] = bf2f(u.x); v[c * 4 + 1] = bf2f(u.x >> 16);
    v[c * 4 + 2] = bf2f(u.y); v[c * 4 + 3] = bf2f(u.y >> 16);
  }
  float s = 0.f;
  #pragma unroll
  for (int i = 0; i < 12; i++) s += v[i];
  #pragma unroll
  for (int o = 32; o > 0; o >>= 1) s += __shfl_xor(s, o);
  const float m = s * (1.f / 768.f);
  float q = 0.f;
  #pragma unroll
  for (int i = 0; i < 12; i++) { v[i] -= m; q += v[i] * v[i]; }
  #pragma unroll
  for (int o = 32; o > 0; o >>= 1) q += __shfl_xor(q, o);
  const float r = rsqrtf(q * (1.f / 768.f) + EPS_);
  #pragma unroll
  for (int c = 0; c < 3; c++) {
    const int d = lane * 4 + c * 256;
    float4 gv = *(const float4*)(g + d);
    float4 bv = *(const float4*)(bb + d);
    uint2 pk;
    pk.x = pack2(v[c * 4 + 0] * r * gv.x + bv.x, v[c * 4 + 1] * r * gv.y + bv.y);
    pk.y = pack2(v[c * 4 + 2] * r * gv.z + bv.z, v[c * 4 + 3] * r * gv.w + bv.w);
    *(uint2*)(p + d) = pk;
  }
}

// ---------------------------------------------------------------------------
// MFMA bf16 GEMM: C[M,N] = [C +] act(A @ W^T + bias). 256x256 tile, 512 thr
// (8 waves 2x4, wave tile 128x64). K mult of 64, N mult of 256. BK=64,
// 2 K-tile LDS dbufs (128 KB), row = 128 B, chunk slot s of row r holds
// k-chunk s^(r&7). K-loop: ONE {vmcnt(0); s_barrier} per K-tile, then stage
// tile kt+1 (full-tile prefetch distance -> vmcnt(0) is pre-covered), then
// free-running compute of tile kt (24 ds_read_b128 + 64 MFMA per wave,
// compiler-scheduled waits, setprio(1) around the MFMA body).
// T1: bijective XCD-chunked swizzle on linear block id (consecutive ids
// share B panel -> per-XCD L2 residency).
// Epilogue: two 64x64 passes via per-wave 8KB LDS slice -> coalesced short8
// stores (+ residual add at readback for ADD).
template <int ACT, bool ADD>
__global__ __launch_bounds__(512) void gemm_mfma(
    const unsigned short* __restrict__ A, int lda, int K,
    const unsigned short* __restrict__ W, int ldw,
    const float* __restrict__ bias,
    unsigned short* __restrict__ C, int ldc,
    const int* __restrict__ mi) {
  const int rows = mi[MI_NTOT] * 64;
  // T1: bijective XCD-chunked remap of the linear block id (m204 formula)
  const int nbx = gridDim.x;
  int id = blockIdx.y * nbx + blockIdx.x;
  {
    const int nwg = nbx * gridDim.y;
    const int q = nwg >> 3, r = nwg & 7;
    const int xcd = id & 7, idx = id >> 3;
    id = (xcd < r ? xcd * (q + 1) : r * (q + 1) + (xcd - r) * q) + idx;
  }
  const int row0 = (id % nbx) * 256;
  if (row0 >= rows) return;
  const int col0 = (id / nbx) * 256;
  __shared__ unsigned short Sh[2 * 32768];   // 2 dbuf x (A 32KB + B 32KB) = 128KB
  const int t = threadIdx.x;
  const int lane = t & 63, w = t >> 6;        // 8 waves
  const int wr = w >> 2, wc = w & 3;          // 2x4 wave grid, tile 128x64
  const int quad = lane >> 4, l15 = lane & 15;
  f32x4 acc[8][4];
  #pragma unroll
  for (int i = 0; i < 8; i++)
    #pragma unroll
    for (int j = 0; j < 4; j++) acc[i][j] = (f32x4){0.f, 0.f, 0.f, 0.f};

  // staging per-thread constants: thread covers rows h*128 + j*64 + sr,
  // slot s = lane&7 holds global k-chunk s ^ (lane>>3)  (row&7 == lane>>3)
  const int sr  = w * 8 + (lane >> 3);
  const int cc8 = ((lane & 7) ^ (lane >> 3)) * 8;

  // fragment ds_read offsets (ushort units); row*64 + slot*8, slot = c^(r&7)
  int aoffm[8], boffn[4];
  #pragma unroll
  for (int m = 0; m < 8; m++) aoffm[m] = (wr * 128 + m * 16 + l15) * 64;
  #pragma unroll
  for (int n = 0; n < 4; n++) boffn[n] = (wc * 64 + n * 16 + l15) * 64;
  const int e7 = l15 & 7;
  const int pq0 = ((quad)     ^ e7) * 8;     // kc=0 chunk slot
  const int pq1 = ((4 + quad) ^ e7) * 8;     // kc=1 chunk slot

  // stage half h (0/1) of matrix (0=A,1=B) for K-tile kt into buffer bi
#define STG(bi_, mat_, h_, kt_)                                                \
  { const unsigned short* gp_ = (mat_) ? W : A;                                \
    const int ld_ = (mat_) ? ldw : lda;                                        \
    const int b0_ = (mat_) ? col0 : row0;                                      \
    _Pragma("unroll")                                                          \
    for (int j_ = 0; j_ < 2; j_++) {                                           \
      const unsigned short* src_ =                                             \
          gp_ + (size_t)(b0_ + (h_) * 128 + j_ * 64 + sr) * ld_ +              \
          (kt_) * 64 + cc8;                                                    \
      __builtin_amdgcn_global_load_lds(                                        \
          (const __attribute__((address_space(1))) void*)src_,                 \
          (__attribute__((address_space(3))) void*)(Sh + (bi_) * 32768 +       \
              (mat_) * 16384 + (h_) * 8192 + j_ * 4096 + w * 512),             \
          16, 0, 0);                                                           \
    } }
#define STG_TILE(bi_, kt_)                                                     \
  { STG(bi_, 0, 0, kt_); STG(bi_, 0, 1, kt_);                                  \
    STG(bi_, 1, 0, kt_); STG(bi_, 1, 1, kt_); }

  const int NT = K >> 6;     // 64-k tiles (call sites: 12 or 32)
  STG_TILE(0, 0);
  for (int kt = 0; kt < NT; kt++) {
    const int cur = kt & 1;
    // tile kt's 8 loads were issued >= one full tile-compute ago (except
    // kt=0) -> vmcnt(0) is pre-covered. Barrier orders all waves' reads of
    // buf[cur^1] (tile kt-1) before the STG below overwrites it.
    asm volatile("s_waitcnt vmcnt(0)\ns_barrier" ::: "memory");
    if (kt + 1 < NT) STG_TILE(cur ^ 1, kt + 1);
    const unsigned short* SA = Sh + cur * 32768;
    const unsigned short* SB = SA + 16384;
    short8 bfr[4][2];
    #pragma unroll
    for (int n = 0; n < 4; n++) {
      bfr[n][0] = *(const short8*)(SB + boffn[n] + pq0);
      bfr[n][1] = *(const short8*)(SB + boffn[n] + pq1);
    }
    __builtin_amdgcn_s_setprio(1);
    #pragma unroll
    for (int m = 0; m < 8; m++) {
      short8 a0 = *(const short8*)(SA + aoffm[m] + pq0);
      short8 a1 = *(const short8*)(SA + aoffm[m] + pq1);
      #pragma unroll
      for (int n = 0; n < 4; n++) {
        acc[m][n] = __builtin_amdgcn_mfma_f32_16x16x32_bf16(a0, bfr[n][0],
                                                            acc[m][n], 0, 0, 0);
        acc[m][n] = __builtin_amdgcn_mfma_f32_16x16x32_bf16(a1, bfr[n][1],
                                                            acc[m][n], 0, 0, 0);
      }
    }
    __builtin_amdgcn_s_setprio(0);
  }
  __syncthreads();           // LDS now dead -> reuse as epilogue bounce
#undef STG
#undef STG_TILE

  // epilogue: C/D layout col = lane&15, row = quad*4 + reg. Two 64x64 passes
  // per wave through its private 8KB slice, then coalesced short8 stores
  // (8 per lane per pass). Residual add (ADD) at readback.
  unsigned short* slice = Sh + w * 4096;
  float bv[4];
  #pragma unroll
  for (int n = 0; n < 4; n++) bv[n] = bias[col0 + wc * 64 + n * 16 + l15];
  #pragma unroll
  for (int p = 0; p < 2; p++) {
    #pragma unroll
    for (int mm = 0; mm < 4; mm++) {
      #pragma unroll
      for (int reg = 0; reg < 4; reg++) {
        const int r64 = mm * 16 + quad * 4 + reg;
        #pragma unroll
        for (int n = 0; n < 4; n++) {
          float x = acc[p * 4 + mm][n][reg] + bv[n];
          if (ACT == 1) x = fmaxf(x, 0.f);
          slice[r64 * 64 + n * 16 + l15] = f2bf(x);
        }
      }
    }
    unsigned short* crow =
        C + (size_t)(row0 + wr * 128 + p * 64) * ldc + col0 + wc * 64;
    #pragma unroll
    for (int i = 0; i < 8; i++) {
      const int j = i * 64 + lane;           // 16B chunk 0..511 of 64x64 tile
      const int r64 = j >> 3, c8 = (j & 7) * 8;
      short8 v = *(const short8*)(slice + j * 8);
      unsigned short* cp = crow + (size_t)r64 * ldc + c8;
      if (ADD) {
        short8 cv = *(const short8*)cp;
        #pragma unroll
        for (int e = 0; e < 8; e++)
          v[e] = (short)f2bf(bf2f((unsigned short)v[e]) +
                             bf2f((unsigned short)cv[e]));
      }
      *(short8*)cp = v;
    }
  }
}

// ---------------------------------------------------------------------------
// VALU GEMM (kept for ragged pe/pd only): C = act(A @ W^T + b)
// AT: 0 fp32 A, 1 bf16 A.  CT: 0 fp32 C, 1 bf16 C.
template <int ACT, int AT, int CT>
__global__ __launch_bounds__(256) void gemm_kernel(
    const void* __restrict__ Av, int lda, int kloop,
    const float* __restrict__ W, int kw, int nreal,
    const float* __restrict__ bias,
    void* __restrict__ Cv, int ldc,
    const int* __restrict__ mi) {
  if ((int)blockIdx.x >= mi[MI_NTOT]) return;
  __shared__ float As[16][68];
  __shared__ float Ws[16][68];
  const int t = threadIdx.x;
  const int tx = t & 15, ty = t >> 4;
  const int lrow = t >> 2, lkg = (t & 3) * 4;
  const size_t row0 = (size_t)blockIdx.x * 64;
  const int col0 = blockIdx.y * 64;
  float acc[4][4] = {};
  for (int k0 = 0; k0 < kloop; k0 += 16) {
    float a4[4];
    if (AT == 0) {
      float4 av = *(const float4*)((const float*)Av + (row0 + lrow) * (size_t)lda + k0 + lkg);
      a4[0] = av.x; a4[1] = av.y; a4[2] = av.z; a4[3] = av.w;
    } else {
      uint2 u = *(const uint2*)((const unsigned short*)Av + (row0 + lrow) * (size_t)lda + k0 + lkg);
      a4[0] = bf2f(u.x); a4[1] = bf2f(u.x >> 16);
      a4[2] = bf2f(u.y); a4[3] = bf2f(u.y >> 16);
    }
    float wv[4];
    const int wn = col0 + lrow;
    #pragma unroll
    for (int i = 0; i < 4; i++) {
      const int k = k0 + lkg + i;
      wv[i] = (wn < nreal && k < kw) ? W[(size_t)wn * kw + k] : 0.f;
    }
    __syncthreads();
    As[lkg + 0][lrow] = a4[0]; As[lkg + 1][lrow] = a4[1];
    As[lkg + 2][lrow] = a4[2]; As[lkg + 3][lrow] = a4[3];
    Ws[lkg + 0][lrow] = wv[0]; Ws[lkg + 1][lrow] = wv[1];
    Ws[lkg + 2][lrow] = wv[2]; Ws[lkg + 3][lrow] = wv[3];
    __syncthreads();
    #pragma unroll
    for (int kk = 0; kk < 16; kk++) {
      float4 av4 = *(const float4*)(&As[kk][ty * 4]);
      float4 wv4 = *(const float4*)(&Ws[kk][tx * 4]);
      float aa[4] = {av4.x, av4.y, av4.z, av4.w};
      float ww[4] = {wv4.x, wv4.y, wv4.z, wv4.w};
      #pragma unroll
      for (int i = 0; i < 4; i++)
        #pragma unroll
        for (int j = 0; j < 4; j++) acc[i][j] += aa[i] * ww[j];
    }
  }
  const int n0 = col0 + tx * 4;
  float bv[4];
  #pragma unroll
  for (int j = 0; j < 4; j++) bv[j] = (n0 + j < nreal) ? bias[n0 + j] : 0.f;
  #pragma unroll
  for (int i = 0; i < 4; i++) {
    float v[4];
    #pragma unroll
    for (int j = 0; j < 4; j++) {
      float x = acc[i][j] + bv[j];
      if (ACT == 1) x = fmaxf(x, 0.f);
      if (ACT == 2) x = tanhf(x);
      v[j] = x;
    }
    if (CT == 0) {
      float* cp = (float*)Cv + (row0 + ty * 4 + i) * (size_t)ldc + n0;
      *(float4*)cp = make_float4(v[0], v[1], v[2], v[3]);
    } else {
      unsigned short* cp = (unsigned short*)Cv + (row0 + ty * 4 + i) * (size_t)ldc + n0;
      uint2 pk; pk.x = pack2(v[0], v[1]); pk.y = pack2(v[2], v[3]);
      *(uint2*)cp = pk;
    }
  }
}

// ---------------------------------------------------------------------------
// MFMA attention, KV-resident: one block per (l, h), 8 waves (512 thr).
// Stage ALL K (global_load_lds, pre-swizzled source -> linear LDS) and V^T
// (manual transpose scatter) once; single barrier; then each wave free-runs
// q-tiles (16 rows/wave, 128/block) x kv-tiles with zero global loads and
// zero barriers (P staging per-wave). O bf16 overwrites Q columns of QKV
// (disjoint from staged K/V columns; each wave owns its rows -> race-free).
// LDS tile swizzle: elem(row,col) at row*64 + ((col>>3)^(row&7))*8 + (col&7).
__global__ __launch_bounds__(512) void attn_kernel(
    unsigned short* __restrict__ QKV, const float* __restrict__ bias2,
    const int* __restrict__ mi) {
  const int ntot = mi[MI_NTOT];
  const int l = blockIdx.x, h = blockIdx.y;
  const int ntk = (ntot + 63) >> 6;     // kv tiles (padded keys masked by bias)
  __shared__ unsigned short Ks[512 * 64];   // K rows [m][d], swizzled
  __shared__ unsigned short Vt[8 * 4096];   // per-tile V^T [d][m], swizzled
  __shared__ unsigned short Ps[8][1024];    // per-wave P / O-bounce
  __shared__ float bs[512];                 // bias column for this l
  const int t = threadIdx.x;
  const int lane = t & 63, w = t >> 6;
  const int quad = lane >> 4, l15 = lane & 15;

  // ---- stage K: linear LDS dst, source chunk pre-swizzled so slot g of row
  // m holds chunk g ^ (m&7) (matches the ds_read swizzle below)
  {
    const int sub = lane >> 3;              // low 3 bits of m
    const int cc = (lane & 7) ^ sub;        // source chunk for this slot
    for (int it = 0; it < ntk; it++) {
      const int m = it * 64 + w * 8 + sub;
      const unsigned short* src =
          QKV + (size_t)(m * L_ + l) * 2304 + 768 + h * 64 + cc * 8;
      __builtin_amdgcn_global_load_lds(
          (const __attribute__((address_space(1))) void*)src,
          (__attribute__((address_space(3))) void*)(Ks + it * 4096 + w * 512),
          16, 0, 0);
    }
  }
  // ---- stage V transposed: thread t -> m = t&63, d in [(t>>6)*8, +8)
  {
    const int m = t & 63;
    const int d0 = (t >> 6) * 8;
    for (int mt = 0; mt < ntk; mt++) {
      short8 v = *(const short8*)(
          QKV + (size_t)((mt * 64 + m) * L_ + l) * 2304 + 1536 + h * 64 + d0);
      #pragma unroll
      for (int i = 0; i < 8; i++) {
        const int d = d0 + i;
        Vt[mt * 4096 + d * 64 + (((m >> 3) ^ (d & 7)) * 8) + (m & 7)] =
            (unsigned short)v[i];
      }
    }
  }
  // ---- stage bias column (padded m already -1e30 from gather)
  bs[t] = bias2[t * 64 + l];
  __syncthreads();

  const int nqt = (ntot + 127) >> 7;
  for (int qt = 0; qt < nqt; qt++) {
    const int qbase = qt * 128 + w * 16;
    if (qbase >= ntot) continue;

    // Q A-frags direct from global (2 x 16B per lane)
    short8 af[2];
    #pragma unroll
    for (int kc = 0; kc < 2; kc++)
      af[kc] = *(const short8*)(
          QKV + (size_t)((qbase + l15) * L_ + l) * 2304 + h * 64 + (kc * 4 + quad) * 8);

    f32x4 oa[4];
    float runmax[4], runsum[4];
    #pragma unroll
    for (int f = 0; f < 4; f++) oa[f] = (f32x4){0.f, 0.f, 0.f, 0.f};
    #pragma unroll
    for (int r2 = 0; r2 < 4; r2++) { runmax[r2] = -3.0e38f; runsum[r2] = 0.f; }

    for (int mt = 0; mt < ntk; mt++) {
      // ---- S = Q @ K^T  (C layout: row q = quad*4+reg, col m = cb*16+l15)
      f32x4 sv[4];
      #pragma unroll
      for (int cb = 0; cb < 4; cb++) {
        sv[cb] = (f32x4){0.f, 0.f, 0.f, 0.f};
        const int mrow = mt * 64 + cb * 16 + l15;
        #pragma unroll
        for (int kc = 0; kc < 2; kc++) {
          short8 bk = *(const short8*)(
              Ks + mrow * 64 + (((kc * 4 + quad) ^ (mrow & 7)) * 8));
          sv[cb] = __builtin_amdgcn_mfma_f32_16x16x32_bf16(af[kc], bk, sv[cb], 0, 0, 0);
        }
      }

      // ---- online softmax (state per q-row = quad*4+reg)
      float bj[4];
      #pragma unroll
      for (int cb = 0; cb < 4; cb++) bj[cb] = bs[mt * 64 + cb * 16 + l15];
      float pj[4][4];   // [cb][reg]
      #pragma unroll
      for (int cb = 0; cb < 4; cb++)
        #pragma unroll
        for (int r2 = 0; r2 < 4; r2++) pj[cb][r2] = sv[cb][r2] * 0.125f + bj[cb];
      float tmax[4];
      #pragma unroll
      for (int r2 = 0; r2 < 4; r2++)
        tmax[r2] = fmaxf(fmaxf(pj[0][r2], pj[1][r2]), fmaxf(pj[2][r2], pj[3][r2]));
      #pragma unroll
      for (int o2 = 1; o2 < 16; o2 <<= 1)
        #pragma unroll
        for (int r2 = 0; r2 < 4; r2++) tmax[r2] = fmaxf(tmax[r2], __shfl_xor(tmax[r2], o2));
      float tsum[4];
      #pragma unroll
      for (int r2 = 0; r2 < 4; r2++) {
        const float nmax = fmaxf(runmax[r2], tmax[r2]);
        const float alpha = __expf(runmax[r2] - nmax);
        runmax[r2] = nmax;
        float s0 = 0.f;
        #pragma unroll
        for (int cb = 0; cb < 4; cb++) { pj[cb][r2] = __expf(pj[cb][r2] - nmax); s0 += pj[cb][r2]; }
        tsum[r2] = s0;
        runsum[r2] *= alpha;
        #pragma unroll
        for (int f = 0; f < 4; f++) oa[f][r2] *= alpha;
      }
      #pragma unroll
      for (int o2 = 1; o2 < 16; o2 <<= 1)
        #pragma unroll
        for (int r2 = 0; r2 < 4; r2++) tsum[r2] += __shfl_xor(tsum[r2], o2);
      #pragma unroll
      for (int r2 = 0; r2 < 4; r2++) runsum[r2] += tsum[r2];

      // ---- P -> per-wave LDS (A-operand layout, bf16)
      #pragma unroll
      for (int cb = 0; cb < 4; cb++) {
        const int m = cb * 16 + l15;
        #pragma unroll
        for (int r2 = 0; r2 < 4; r2++) {
          const int q = quad * 4 + r2;
          Ps[w][q * 64 + (((m >> 3) ^ (q & 7)) * 8) + (m & 7)] = f2bf(pj[cb][r2]);
        }
      }
      // ---- O += P @ V
      short8 pa[2];
      #pragma unroll
      for (int kc = 0; kc < 2; kc++)
        pa[kc] = *(const short8*)(
            &Ps[w][l15 * 64 + (((kc * 4 + quad) ^ (l15 & 7)) * 8)]);
      #pragma unroll
      for (int f = 0; f < 4; f++) {
        const int d = f * 16 + l15;
        #pragma unroll
        for (int kc = 0; kc < 2; kc++) {
          short8 bv = *(const short8*)(
              Vt + mt * 4096 + d * 64 + (((kc * 4 + quad) ^ (d & 7)) * 8));
          oa[f] = __builtin_amdgcn_mfma_f32_16x16x32_bf16(pa[kc], bv, oa[f], 0, 0, 0);
        }
      }
    }

    // ---- epilogue: normalize, bounce through per-wave Ps, 16B stores
    #pragma unroll
    for (int r2 = 0; r2 < 4; r2++) {
      const float inv = 1.f / runsum[r2];
      const int q = quad * 4 + r2;
      #pragma unroll
      for (int f = 0; f < 4; f++)
        Ps[w][q * 64 + f * 16 + l15] = f2bf(oa[f][r2] * inv);
    }
    #pragma unroll
    for (int i = 0; i < 2; i++) {
      const int j = lane + i * 64;          // 16B chunk index 0..127
      const int q = j >> 3, c8 = j & 7;
      short8 v = *(const short8*)(&Ps[w][j * 8]);
      *(short8*)(QKV + (size_t)((qbase + q) * L_ + l) * 2304 + h * 64 + c8 * 8) = v;
    }
  }
}

// ---------------------------------------------------------------------------
__global__ __launch_bounds__(256) void score_kernel(const unsigned short* __restrict__ X,
                                                    const float* __restrict__ em,
                                                    float* __restrict__ Sv) {
  const int j = blockIdx.x;
  const int t = threadIdx.x;
  __shared__ float red[4];
  float part = 0.f;
  for (int c = 0; c < 3; c++) {
    const int d = t + c * 256;
    const unsigned short* p = X + (size_t)j * L_ * D_ + d;
    float s = 0.f;
    for (int l = 0; l < L_; l++) s += bf2f(p[l * D_]);
    const float diff = s * (1.f / 64.f) - em[j * D_ + d];
    part += diff * diff;
  }
  const float tot = blockSum256(part, red);
  if (t == 0) Sv[j] = tot;
}

// ---------------------------------------------------------------------------
__global__ __launch_bounds__(256) void finalize_kernel(const float* __restrict__ Sv,
                                                       int* __restrict__ mi,
                                                       float* __restrict__ out) {
  const int t = threadIdx.x;
  if (t < B_) {
    const int nr = mi[MI_NRESP + t];
    float best = 3.0e38f; int bi = 0;
    for (int j = 0; j < nr; j++) {
      const float v = Sv[j];
      if (v < best) { best = v; bi = j; }
    }
    mi[MI_NODE + t] = bi + 1;
    int next = nr / 20; if (next < 1) next = 1;
    out[OUT_NTL + t] = (float)(1 + next);
  }
  if (t == 0) out[OUT_NEA] = 0.f;
  __syncthreads();
  for (int idx = t; idx < B_ * T_; idx += 256) {
    const int b = idx >> 5, tt = idx & 31;
    out[OUT_OH + idx] = (tt == 0 || tt == mi[MI_NODE + b]) ? 1.f : 0.f;
  }
}

// ---------------------------------------------------------------------------
__global__ __launch_bounds__(256) void maskout_kernel(const float* __restrict__ am,
                                                      const int* __restrict__ mi,
                                                      float* __restrict__ out) {
  const int idx = blockIdx.x * 256 + threadIdx.x;
  const int b = idx >> 11, rem = idx & 2047;
  const int tt = rem >> 6, l = rem & 63;
  const int node = mi[MI_NODE + b];
  out[OUT_EXT + idx] = (tt == 0 || tt == node) ? 1.f : 0.f;
  float nm;
  if (tt == 0)      nm = am[(b * T_) * L_ + l];
  else if (tt == 1) nm = am[(b * T_ + node) * L_ + l];
  else              nm = 0.f;
  out[OUT_NMSK + idx] = nm;
}

// ---------------------------------------------------------------------------
__global__ __launch_bounds__(192) void newemb_kernel(const float* __restrict__ emb,
                                                     const int* __restrict__ mi,
                                                     float* __restrict__ out) {
  const int blk = blockIdx.x;
  const int b = blk >> 11, rem = blk & 2047;
  const int tt = rem >> 6, l = rem & 63;
  const int srct = (tt == 1) ? mi[MI_NODE + b] : 0;
  const float4 v = ((const float4*)(emb + (size_t)((b * T_ + srct) * L_ + l) * D_))[threadIdx.x];
  float* dst = out + OUT_NEMB + (size_t)blk * D_ + threadIdx.x * 4;
  dst[0] = v.x; dst[1] = v.y; dst[2] = v.z; dst[3] = v.w;
}

// ===========================================================================
extern "C" void kernel_launch(void* const* d_in, const int* in_sizes, int n_in,
                              void* d_out, int out_size, void* d_ws, size_t ws_size,
                              hipStream_t stream) {
  (void)in_sizes; (void)n_in; (void)out_size; (void)ws_size;
  const int*   tl  = (const int*)d_in[0];
  const float* emb = (const float*)d_in[1];
  const float* am  = (const float*)d_in[2];
  const float* P[28];
  for (int i = 0; i < 28; i++) P[i] = (const float*)d_in[3 + i];

  float* wsf   = (float*)d_ws;
  int*   mi    = (int*)d_ws;
  float* bias2 = wsf + WS_BIAS2;
  float* emean = wsf + WS_EMEAN;
  float* Sv    = wsf + WS_S;
  unsigned short* Wst = (unsigned short*)(wsf + WS_WST);
  unsigned short* BIG = (unsigned short*)(wsf + WS_BIG);
  float* Zb    = wsf + WS_BIG;                      // fp32 Z overlay (enc->dec)
  float* out   = (float*)d_out;
  unsigned short* X = (unsigned short*)(out + OUT_XSCR);  // bf16 residual

  meta_kernel<<<1, 64, 0, stream>>>(tl, mi);
  gather_kernel<<<NP_ * L_, 192, 0, stream>>>(emb, am, mi, X, bias2);
  emean_kernel<<<NP_, 256, 0, stream>>>(X, emean);

  const int RTM = NP_ * 64 / 256;  // 128 row tiles (256 rows each)
  const int LNB = NP_ * L_ / 4;    // 8192 ln blocks (4 rows each)
  for (int s = 0; s < 2; s++) {
    const float* const* q = P + s * 12;
    for (int i = 0; i < 2; i++) {
      // QKV: X -> BIG [rows, 2304]
      w2bf_kernel<<<(3 * D_ * D_) / 1024, 256, 0, stream>>>(q[0] + (size_t)i * 3 * D_ * D_, Wst);
      gemm_mfma<0, false><<<dim3(RTM, 9), 512, 0, stream>>>(
          X, D_, D_, Wst, D_, q[1] + i * 3 * D_, BIG, 3 * D_, mi);
      attn_kernel<<<dim3(L_, H_), 512, 0, stream>>>(BIG, bias2, mi);
      // out-proj: O (Q cols of BIG, lda=2304) -> += X
      w2bf_kernel<<<(D_ * D_) / 1024, 256, 0, stream>>>(q[2] + (size_t)i * D_ * D_, Wst);
      gemm_mfma<0, true><<<dim3(RTM, 3), 512, 0, stream>>>(
          BIG, 3 * D_, D_, Wst, D_, q[3] + i * D_, X, D_, mi);
      ln_kernel<<<LNB, 256, 0, stream>>>(X, q[4] + i * D_, q[5] + i * D_, mi);
      // FFN1: X -> hidden BIG [rows, 2048] (relu)
      w2bf_kernel<<<(F_ * D_) / 1024, 256, 0, stream>>>(q[6] + (size_t)i * F_ * D_, Wst);
      gemm_mfma<1, false><<<dim3(RTM, 8), 512, 0, stream>>>(
          X, D_, D_, Wst, D_, q[7] + i * F_, BIG, F_, mi);
      // FFN2: hidden -> += X
      w2bf_kernel<<<(D_ * F_) / 1024, 256, 0, stream>>>(q[8] + (size_t)i * D_ * F_, Wst);
      gemm_mfma<0, true><<<dim3(RTM, 3), 512, 0, stream>>>(
          BIG, F_, F_, Wst, F_, q[9] + i * D_, X, D_, mi);
      ln_kernel<<<LNB, 256, 0, stream>>>(X, q[10] + i * D_, q[11] + i * D_, mi);
    }
    if (s == 0) {
      // z = tanh(h @ pe_w^T + pe_b) -> Z fp32 (stride 128, cols 100..127 = 0)
      gemm_kernel<2, 1, 0><<<dim3(NP_, 2), 256, 0, stream>>>(
          X, D_, D_, P[24], D_, ZR_, P[25], Zb, ZP_, mi);
      // zd = tanh(z @ pd_w^T + pd_b) -> X bf16 (decoder input)
      gemm_kernel<2, 0, 1><<<dim3(NP_, 12), 256, 0, stream>>>(
          Zb, ZP_, ZP_, P[26], ZR_, D_, P[27], X, D_, mi);
    }
  }

  score_kernel<<<NP_, 256, 0, stream>>>(X, emean, Sv);
  finalize_kernel<<<1, 256, 0, stream>>>(Sv, mi, out);
  maskout_kernel<<<128, 256, 0, stream>>>(am, mi, out);
  newemb_kernel<<<B_ * T_ * L_, 192, 0, stream>>>(emb, mi, out);
}